// Round 5
// baseline (1112.829 us; speedup 1.0000x reference)
//
#include <hip/hip_runtime.h>

// ---- problem constants (from reference) ----
#define N_LANEC  20000
#define N_AGENTC 4000
#define PTS      20
#define FD       8
#define HD       128
#define E_LLC    640000
#define E_AAC    128000
#define E_LAC    200000

#define CAP_LL 80     // deg ~ Binom(640k, 1/20k): mean 32; P(>80) < 1e-11
#define CAP_AA 80     // mean 32
#define CAP_LA 112    // mean 50; P(>112) < 1e-12

typedef unsigned short u16;
typedef unsigned int   u32;
typedef __attribute__((ext_vector_type(8))) short short8;   // 8 bf16 (4 VGPRs)
typedef __attribute__((ext_vector_type(4))) float f32x4;    // MFMA C/D

__device__ __forceinline__ float bf2f(u16 u) {
    union { u32 i; float f; } c; c.i = ((u32)u) << 16; return c.f;
}
__device__ __forceinline__ u16 f2bf(float f) {
    union { float f; u32 i; } c; c.f = f;
    u32 r = c.i + 0x7FFFu + ((c.i >> 16) & 1u);   // RNE
    return (u16)(r >> 16);
}
__device__ __forceinline__ float ldf(const void* p, size_t i, int isf) {
    return isf ? ((const float*)p)[i] : bf2f(((const u16*)p)[i]);
}

// per-block input dtype detection (fp32 on this dataset)
__device__ __forceinline__ int detect_isf(const u32* x) {
    __shared__ int scnt;
    if (threadIdx.x == 0) scnt = 0;
    __syncthreads();
    u32 w = x[threadIdx.x & 255];
    int e = (int)((w >> 7) & 0xFFu);
    int ok = (e == 0) || (e >= 100 && e <= 140);
    atomicAdd(&scnt, ok);
    __syncthreads();
    return (scnt >= 200) ? 0 : 1;   // 1 = fp32
}

#define NE_TOT (E_LLC + E_AAC + E_LAC)
#define NDEG   (N_LANEC + 2 * N_AGENTC)   // 28000 compact counters

// ---------------------------------------------------------------------------
// K1: enc-weight swizzle + biases + dflag. (deg zeroing gone: range-fill
// zeroes its counters in LDS — no global deg atomics anywhere anymore.)
// ---------------------------------------------------------------------------
#define SWZ1_TOTAL  75264          // 4*16384 + 2*4096 + 12*128
#define SWZ1_BLOCKS 294            // == SWZ1_TOTAL/256 exactly
struct SwzArgs {
    const void* p[18]; u16* dst; const u32* lane_pts; int* dflag;
};
__global__ __launch_bounds__(256) void swz_kernel(SwzArgs a)
{
    const int tid = threadIdx.x;
    const int idx = blockIdx.x * 256 + tid;
    const int isf = detect_isf(a.lane_pts);
    if (blockIdx.x == 0 && tid == 0) *a.dflag = isf;

    const int sizes[18] = {16384,16384,16384,16384,4096,4096,
                           128,128,128,128,128,128,128,128,128,128,128,128};
    const int dsts[18]  = {0,16384,32768,49152,212992,217088,
                           221184,221312,221440,221568,221696,221824,
                           221952,222080,222208,222336,222464,222592};
    int seg = 0, rem = idx;
    while (rem >= sizes[seg]) { rem -= sizes[seg]; seg++; }
    if (seg >= 6) { a.dst[dsts[seg] + rem] = f2bf(ldf(a.p[seg], rem, isf)); return; }
    const int klim   = (seg < 4) ? 128 : 8;
    const int kshift = (seg < 4) ? 2 : 0;
    int j    = rem & 7;
    int lane = (rem >> 3) & 63;
    int t2   = rem >> 9;
    int ks   = t2 & ((1 << kshift) - 1);
    int nt   = t2 >> kshift;
    int k = ks * 32 + ((lane >> 4) << 3) + j;
    int n = nt * 16 + (lane & 15);
    a.dst[dsts[seg] + rem] = (k < klim) ? f2bf(ldf(a.p[seg], (size_t)k * HD + n, isf)) : (u16)0;
}

// ---------------------------------------------------------------------------
// K2: PointNet encoders + range-partitioned edge fill + GNN-weight swizzle.
//
// Fill redesign (r4->r5): the 968k device-scope atomicAdds ran at ~5.8/cycle
// chip-wide (fabric atomic throughput) = ~70us floor; layout padding was
// proven neutral (r2). New scheme: 32 persistent blocks each own 875 of the
// 28000 destination counters; each scans only the edge lists overlapping its
// range, allocates positions with LDS atomics (private, fast), writes col
// entries range-locally (region stays in one L2, written back once) and deg
// once with plain stores. ZERO global atomics.
// ---------------------------------------------------------------------------
#define NRANGE 32
#define RNG    875                                     // 28000/32
#define ENC_BLOCKS   ((N_LANEC + N_AGENTC) / 4)        // 6000
#define GSWZ_TOTAL   147456                            // 3*32768 + 3*16384
#define GSWZ_BLOCKS  576                               // == GSWZ_TOTAL/256
#define AUX2         (NRANGE + GSWZ_BLOCKS)            // 608
#define EF_TOTAL     (ENC_BLOCKS + AUX2)               // 6608

struct EncFillArgs {
    const void* x0; const void* x1;
    const u16 *w1a, *b1a, *w2a, *b2a, *w3a, *b3a;
    const u16 *w1b, *b1b, *w2b, *b2b, *w3b, *b3b;
    u16 *out0, *out1;
    const int* dflag;
    const int *e_ll, *e_aa, *e_la;
    int *deg;                      // compact: deg[g], g in [0,28000)
    u16 *col_ll, *col_aa, *col_la;
    const void* gsrc[6];
    u16* swzdst;
};

// scan one edge list; keep edges with local dst in [lo,hi); LDS-alloc position
template<int CAP>
__device__ __forceinline__ void scan_seg(
    const int* __restrict__ srcp, const int* __restrict__ dstp, int E,
    int lo, int hi, int* __restrict__ cnt, u16* __restrict__ col)
{
    const int tid = threadIdx.x;
    for (int base = tid * 16; base < E; base += 256 * 16) {
        #pragma unroll
        for (int q = 0; q < 4; q++) {
            const int idx = base + q * 4;
            if (idx < E) {
                const int4 d4 = *(const int4*)&dstp[idx];
                const int dd[4] = {d4.x, d4.y, d4.z, d4.w};
                #pragma unroll
                for (int c = 0; c < 4; c++) {
                    const int g = dd[c];
                    if (g >= lo && g < hi) {
                        const int p = atomicAdd(&cnt[g - lo], 1);
                        if (p < CAP) col[(size_t)g * CAP + p] = (u16)srcp[idx + c];
                    }
                }
            }
        }
    }
}

__device__ void fill_range(const EncFillArgs& a, int* cnt, int r)
{
    const int tid = threadIdx.x;
    const int g0 = r * RNG, g1 = g0 + RNG;
    for (int j = tid; j < RNG; j += 256) cnt[j] = 0;
    __syncthreads();
    // global counter id g: ll = dst, aa = 20000+dst, la = 24000+dst
    if (g0 < N_LANEC)
        scan_seg<CAP_LL>(a.e_ll, a.e_ll + E_LLC, E_LLC,
                         g0, g1, cnt, a.col_ll);
    if (g1 > N_LANEC && g0 < N_LANEC + N_AGENTC)
        scan_seg<CAP_AA>(a.e_aa, a.e_aa + E_AAC, E_AAC,
                         g0 - N_LANEC, g1 - N_LANEC, cnt, a.col_aa);
    if (g1 > N_LANEC + N_AGENTC)
        scan_seg<CAP_LA>(a.e_la, a.e_la + E_LAC, E_LAC,
                         g0 - N_LANEC - N_AGENTC, g1 - N_LANEC - N_AGENTC,
                         cnt, a.col_la);
    __syncthreads();
    for (int j = tid; j < RNG; j += 256) a.deg[g0 + j] = cnt[j];
}

__device__ __forceinline__ void gswz(const EncFillArgs& a, int gb)
{
    const int isf = *a.dflag;
    int idx = gb * 256 + threadIdx.x;
    const int sizes[6] = {32768,16384,32768,16384,32768,16384};
    const int dsts[6]  = {65536,98304,114688,147456,163840,196608};
    int seg = 0, rem = idx;
    while (rem >= sizes[seg]) { rem -= sizes[seg]; seg++; }
    const int kshift = (seg & 1) ? 2 : 3;
    const int klim   = (seg & 1) ? 128 : 256;
    int j    = rem & 7;
    int lane = (rem >> 3) & 63;
    int t2   = rem >> 9;
    int ks   = t2 & ((1 << kshift) - 1);
    int nt   = t2 >> kshift;
    int k = ks * 32 + ((lane >> 4) << 3) + j;
    int n = nt * 16 + (lane & 15);
    a.swzdst[dsts[seg] + rem] =
        (k < klim) ? f2bf(ldf(a.gsrc[seg], (size_t)k * HD + n, isf)) : (u16)0;
}

__device__ void enc_body(const EncFillArgs& fa, u16* smem, int bid)
{
    const int tid = threadIdx.x;
    const int NT = 4;
    u16 (*a_lds)[HD + 8] = (u16 (*)[HD + 8])smem;               // 80 x 136 u16
    int (*msI)[HD]       = (int (*)[HD])(smem + 80 * (HD + 8)); // 4 x 128 int

    const int isf = *fa.dflag;
    const int isLane = (bid < N_LANEC / 4);
    const void* x  = isLane ? fa.x0 : fa.x1;
    const u16* w1s = isLane ? fa.w1a : fa.w1b;
    const u16* b1  = isLane ? fa.b1a : fa.b1b;
    const u16* w2s = isLane ? fa.w2a : fa.w2b;
    const u16* b2  = isLane ? fa.b2a : fa.b2b;
    const u16* w3s = isLane ? fa.w3a : fa.w3b;
    const u16* b3  = isLane ? fa.b3a : fa.b3b;
    u16* out = isLane ? fa.out0 : fa.out1;
    const int n0 = (isLane ? bid : bid - N_LANEC / 4) * NT;

    const int lane = tid & 63;
    const int wv   = tid >> 6;
    const int l15  = lane & 15;
    const int quad = lane >> 4;

    for (int idx = tid; idx < NT * HD; idx += 256) ((int*)msI)[idx] = 0;

    short8 afr[5];
    #pragma unroll
    for (int mt = 0; mt < 5; mt++) afr[mt] = (short8){0,0,0,0,0,0,0,0};
    if (quad == 0) {
        #pragma unroll
        for (int mt = 0; mt < 5; mt++) {
            const int m  = mt * 16 + l15;
            const int nn = m / 20;
            const size_t xb = ((size_t)n0 * 20 + m) * 8;
            const size_t rb = (((size_t)(n0 + nn)) * 20 + 19) * 8;
            float f[8];
            if (isf) {
                const float* xf = (const float*)x;
                const float4 lo = *(const float4*)(xf + xb);
                const float4 hi = *(const float4*)(xf + xb + 4);
                f[0] = lo.x - xf[rb]; f[1] = lo.y - xf[rb + 1];
                f[2] = lo.z; f[3] = lo.w;
                f[4] = hi.x; f[5] = hi.y; f[6] = hi.z; f[7] = hi.w;
            } else {
                const u16* xu = (const u16*)x;
                #pragma unroll
                for (int k = 0; k < 8; k++) f[k] = bf2f(xu[xb + k]);
                f[0] -= bf2f(xu[rb]); f[1] -= bf2f(xu[rb + 1]);
            }
            short8 av;
            #pragma unroll
            for (int k = 0; k < 8; k++) av[k] = (short)f2bf(f[k]);
            afr[mt] = av;
        }
    }
    #pragma unroll
    for (int nt2 = 0; nt2 < 2; nt2++) {
        const int ntg = wv * 2 + nt2;
        const float b1v = bf2f(b1[ntg * 16 + l15]);
        const short8 bf = *(const short8*)&w1s[(((size_t)ntg) * 64 + lane) * 8];
        #pragma unroll
        for (int mt = 0; mt < 5; mt++) {
            f32x4 c = { b1v, b1v, b1v, b1v };
            c = __builtin_amdgcn_mfma_f32_16x16x32_bf16(afr[mt], bf, c, 0, 0, 0);
            #pragma unroll
            for (int r = 0; r < 4; r++)
                a_lds[mt * 16 + quad * 4 + r][ntg * 16 + l15] = f2bf(fmaxf(c[r], 0.f));
        }
    }
    __syncthreads();                                   // barrier 1

    short8 bfr[2][4];
    float b2v[2];
    #pragma unroll
    for (int nt2 = 0; nt2 < 2; nt2++) {
        const int ntg = wv * 2 + nt2;
        b2v[nt2] = bf2f(b2[ntg * 16 + l15]);
        #pragma unroll
        for (int ks = 0; ks < 4; ks++)
            bfr[nt2][ks] = *(const short8*)&w2s[(((size_t)(ntg * 4 + ks)) * 64 + lane) * 8];
    }
    const int col0 = (wv * 2 + 0) * 16 + l15;
    const int col1 = (wv * 2 + 1) * 16 + l15;
    float rm0 = 0.f, rm1 = 0.f;
    int curnode = 0;
    for (int mt = 0; mt < 5; mt++) {
        short8 af[4];
        #pragma unroll
        for (int ks = 0; ks < 4; ks++)
            af[ks] = *(const short8*)&a_lds[mt * 16 + l15][ks * 32 + quad * 8];
        f32x4 c0 = { b2v[0], b2v[0], b2v[0], b2v[0] };
        f32x4 c1 = { b2v[1], b2v[1], b2v[1], b2v[1] };
        #pragma unroll
        for (int ks = 0; ks < 4; ks++) {
            c0 = __builtin_amdgcn_mfma_f32_16x16x32_bf16(af[ks], bfr[0][ks], c0, 0, 0, 0);
            c1 = __builtin_amdgcn_mfma_f32_16x16x32_bf16(af[ks], bfr[1][ks], c1, 0, 0, 0);
        }
        #pragma unroll
        for (int r = 0; r < 4; r++) {
            const int m = mt * 16 + quad * 4 + r;
            const int nd = m / PTS;
            if (nd != curnode) {
                atomicMax(&msI[curnode][col0], __float_as_int(rm0));
                atomicMax(&msI[curnode][col1], __float_as_int(rm1));
                rm0 = 0.f; rm1 = 0.f; curnode = nd;
            }
            rm0 = fmaxf(rm0, c0[r]);
            rm1 = fmaxf(rm1, c1[r]);
        }
    }
    atomicMax(&msI[curnode][col0], __float_as_int(rm0));
    atomicMax(&msI[curnode][col1], __float_as_int(rm1));
    __syncthreads();                                   // barrier 2

    short8 a3[4];
    #pragma unroll
    for (int ks = 0; ks < 4; ks++) {
        short8 av = (short8){0,0,0,0,0,0,0,0};
        if (l15 < NT) {
            const int* row = &msI[l15][ks * 32 + quad * 8];
            #pragma unroll
            for (int k = 0; k < 8; k++) av[k] = (short)f2bf(__int_as_float(row[k]));
        }
        a3[ks] = av;
    }
    #pragma unroll
    for (int nt2 = 0; nt2 < 2; nt2++) {
        const int ntg = wv * 2 + nt2;
        const float b3v = bf2f(b3[ntg * 16 + l15]);
        f32x4 c = { b3v, b3v, b3v, b3v };
        #pragma unroll
        for (int ks = 0; ks < 4; ks++) {
            short8 b = *(const short8*)&w3s[(((size_t)(ntg * 4 + ks)) * 64 + lane) * 8];
            c = __builtin_amdgcn_mfma_f32_16x16x32_bf16(a3[ks], b, c, 0, 0, 0);
        }
        #pragma unroll
        for (int r = 0; r < 4; r++) {
            const int row = quad * 4 + r;
            if (row < NT)
                out[(size_t)(n0 + row) * HD + ntg * 16 + l15] = f2bf(fmaxf(c[r], 0.f));
        }
    }
}

__global__ __launch_bounds__(256) void enc_fill_kernel(EncFillArgs a)
{
    __shared__ __align__(16) u16 smem[11904];   // enc: 80x136 u16 + 4x128 int
    const int i = (int)blockIdx.x;
    if (i < NRANGE)      { fill_range(a, (int*)smem, i); return; }
    if (i < AUX2)        { gswz(a, i - NRANGE);          return; }
    enc_body(a, smem, i - AUX2);
}

// ---------------------------------------------------------------------------
// K3/K4: fused gather + edge-GNN MLP (r4-verified vectorized gather).
// OUT_MODE: 0 = f32, 1 = bf16, 2 = f32 + bf16 copy.
// ---------------------------------------------------------------------------
template<int OUT_MODE>
__device__ __forceinline__ void gnn_body(
    int n0, const u16* __restrict__ node, const u16* __restrict__ src,
    const u16* __restrict__ col, const int* __restrict__ deg, int cap,
    const u16* __restrict__ w1s, const u16* __restrict__ b1,
    const u16* __restrict__ w2s, const u16* __restrict__ b2,
    void* __restrict__ outv, u16* __restrict__ out2)
{
    __shared__ __align__(16) u16 cats[16][2 * HD + 8];
    __shared__ __align__(16) u16 hb[16][HD + 8];
    const int tid  = threadIdx.x;
    const int lane = tid & 63;
    const int wv   = tid >> 6;
    const int l15  = lane & 15;
    const int quad = lane >> 4;

    const u32* node32 = (const u32*)node;
    for (int idx = tid; idx < 16 * 64; idx += 256) {
        int nn = idx >> 6, k2 = idx & 63;
        *(u32*)&cats[nn][k2 * 2] = node32[(size_t)(n0 + nn) * 64 + k2];
    }
    const int slot = lane >> 4;      // neighbor sub-stream 0..3
    const int fg   = lane & 15;      // feature group: feats fg*8..fg*8+7
    for (int t = 0; t < 4; t++) {
        const int dn = wv * 4 + t;
        const int d  = n0 + dn;
        const int dv = deg[d];
        const int cnt = min(dv, cap);
        const u16* cb = col + (size_t)d * cap;
        float acc[8] = {0.f,0.f,0.f,0.f,0.f,0.f,0.f,0.f};
        for (int e = slot; e < cnt; e += 4) {
            const int r = (int)cb[e];
            const short8 v = *(const short8*)&src[(size_t)r * HD + fg * 8];
            #pragma unroll
            for (int k = 0; k < 8; k++) acc[k] += bf2f((u16)v[k]);
        }
        const float inv = 1.f / fmaxf((float)dv, 1.f);
        #pragma unroll
        for (int k = 0; k < 8; k++) {
            acc[k] += __shfl_xor(acc[k], 16);
            acc[k] += __shfl_xor(acc[k], 32);
        }
        if (slot == 0) {
            short8 o;
            #pragma unroll
            for (int k = 0; k < 8; k++) o[k] = (short)f2bf(acc[k] * inv);
            *(short8*)&cats[dn][HD + fg * 8] = o;
        }
    }
    __syncthreads();

    #pragma unroll
    for (int nt2 = 0; nt2 < 2; nt2++) {
        const int ntg = wv * 2 + nt2;
        const float b1v = bf2f(b1[ntg * 16 + l15]);
        f32x4 c = { b1v, b1v, b1v, b1v };
        #pragma unroll
        for (int ks = 0; ks < 8; ks++) {
            short8 a = *(const short8*)&cats[l15][ks * 32 + quad * 8];
            short8 b = *(const short8*)&w1s[(((size_t)(ntg * 8 + ks)) * 64 + lane) * 8];
            c = __builtin_amdgcn_mfma_f32_16x16x32_bf16(a, b, c, 0, 0, 0);
        }
        #pragma unroll
        for (int r = 0; r < 4; r++)
            hb[quad * 4 + r][ntg * 16 + l15] = f2bf(fmaxf(c[r], 0.f));
    }
    __syncthreads();

    #pragma unroll
    for (int nt2 = 0; nt2 < 2; nt2++) {
        const int ntg = wv * 2 + nt2;
        const float b2v = bf2f(b2[ntg * 16 + l15]);
        f32x4 c = { b2v, b2v, b2v, b2v };
        #pragma unroll
        for (int ks = 0; ks < 4; ks++) {
            short8 a = *(const short8*)&hb[l15][ks * 32 + quad * 8];
            short8 b = *(const short8*)&w2s[(((size_t)(ntg * 4 + ks)) * 64 + lane) * 8];
            c = __builtin_amdgcn_mfma_f32_16x16x32_bf16(a, b, c, 0, 0, 0);
        }
        #pragma unroll
        for (int r = 0; r < 4; r++) {
            const int row = quad * 4 + r;
            size_t o = (size_t)(n0 + row) * HD + ntg * 16 + l15;
            float res = bf2f(node[o]) + fmaxf(c[r], 0.f);
            if (OUT_MODE == 1) ((u16*)outv)[o] = f2bf(res);
            else {
                ((float*)outv)[o] = res;
                if (OUT_MODE == 2) out2[o] = f2bf(res);
            }
        }
    }
}

struct Gnn2Args {
    const u16* node_ll; const u16* col_ll; const int* deg_ll;
    const u16 *w1_ll, *b1_ll, *w2_ll, *b2_ll; float* out_ll; u16* fin_ll;
    const u16* node_aa; const u16* col_aa; const int* deg_aa;
    const u16 *w1_aa, *b1_aa, *w2_aa, *b2_aa; u16* out_aa;
};
__global__ __launch_bounds__(256) void gnn2_kernel(Gnn2Args a) {
    if (blockIdx.x < N_LANEC / 16)
        gnn_body<2>(blockIdx.x * 16, a.node_ll, a.node_ll, a.col_ll, a.deg_ll, CAP_LL,
                    a.w1_ll, a.b1_ll, a.w2_ll, a.b2_ll, a.out_ll, a.fin_ll);
    else
        gnn_body<1>((blockIdx.x - N_LANEC / 16) * 16, a.node_aa, a.node_aa,
                    a.col_aa, a.deg_aa, CAP_AA,
                    a.w1_aa, a.b1_aa, a.w2_aa, a.b2_aa, a.out_aa, nullptr);
}
__global__ __launch_bounds__(256) void gnn_la_kernel(
    const u16* node, const u16* src, const u16* col, const int* deg,
    const u16* w1s, const u16* b1, const u16* w2s, const u16* b2, float* out) {
    gnn_body<0>(blockIdx.x * 16, node, src, col, deg, CAP_LA,
                w1s, b1, w2s, b2, out, nullptr);
}

// ---------------------------------------------------------------------------
extern "C" void kernel_launch(void* const* d_in, const int* in_sizes, int n_in,
                              void* d_out, int out_size, void* d_ws, size_t ws_size,
                              hipStream_t stream)
{
    const void* lane_pts   = d_in[0];
    const void* agent_hist = d_in[1];
    const int* e_ll = (const int*)d_in[2];
    const int* e_aa = (const int*)d_in[3];
    const int* e_la = (const int*)d_in[4];
    const void *lw1 = d_in[5],  *lb1 = d_in[6],  *lw2 = d_in[7],  *lb2 = d_in[8],
               *lw3 = d_in[9],  *lb3 = d_in[10];
    const void *aw1 = d_in[11], *ab1 = d_in[12], *aw2 = d_in[13], *ab2 = d_in[14],
               *aw3 = d_in[15], *ab3 = d_in[16];
    const void *llw1 = d_in[17], *llb1 = d_in[18], *llw2 = d_in[19], *llb2 = d_in[20];
    const void *aaw1 = d_in[21], *aab1 = d_in[22], *aaw2 = d_in[23], *aab2 = d_in[24];
    const void *law1 = d_in[25], *lab1 = d_in[26], *law2 = d_in[27], *lab2 = d_in[28];

    // ---- workspace layout ----
    #define SWZ_TOTAL 222720
    u16* sp = (u16*)d_ws;
    u16* swzbase = sp; sp += SWZ_TOTAL;
    u16* llw1s = swzbase + 65536;
    u16* llw2s = swzbase + 98304;
    u16* aaw1s = swzbase + 114688;
    u16* aaw2s = swzbase + 147456;
    u16* law1s = swzbase + 163840;
    u16* law2s = swzbase + 196608;
    u16* lw1s  = swzbase + 212992;
    u16* aw1s  = swzbase + 217088;
    u16* lw2s  = swzbase + 0;
    u16* aw2s  = swzbase + 16384;
    u16* lw3s  = swzbase + 32768;
    u16* aw3s  = swzbase + 49152;
    u16* lb1b  = swzbase + 221184;
    u16* lb2b  = swzbase + 221312;
    u16* lb3b  = swzbase + 221440;
    u16* ab1b  = swzbase + 221568;
    u16* ab2b  = swzbase + 221696;
    u16* ab3b  = swzbase + 221824;
    u16* llb1b = swzbase + 221952;
    u16* llb2b = swzbase + 222080;
    u16* aab1b = swzbase + 222208;
    u16* aab2b = swzbase + 222336;
    u16* lab1b = swzbase + 222464;
    u16* lab2b = swzbase + 222592;
    int* ip = (int*)sp;
    int* dflag = ip; ip += 4;
    int* deg   = ip; ip += NDEG;            // compact 28000 ints
    u16* hp = (u16*)ip;
    u16* col_ll = hp; hp += (size_t)N_LANEC * CAP_LL;
    u16* col_aa = hp; hp += (size_t)N_AGENTC * CAP_AA;
    u16* col_la = hp; hp += (size_t)N_AGENTC * CAP_LA;
    u16* lane_enc  = hp; hp += (size_t)N_LANEC * HD;
    u16* agent_enc = hp; hp += (size_t)N_AGENTC * HD;
    u16* agent_mid = hp; hp += (size_t)N_AGENTC * HD;
    u16* lane_fin  = hp; hp += (size_t)N_LANEC * HD;

    float* out_lane  = (float*)d_out;
    float* out_agent = (float*)d_out + (size_t)N_LANEC * HD;

    // ---- K1 ----
    SwzArgs sa;
    sa.p[0] = lw2; sa.p[1] = aw2; sa.p[2] = lw3; sa.p[3] = aw3;
    sa.p[4] = lw1; sa.p[5] = aw1;
    sa.p[6] = lb1;  sa.p[7] = lb2;  sa.p[8] = lb3;
    sa.p[9] = ab1;  sa.p[10] = ab2; sa.p[11] = ab3;
    sa.p[12] = llb1; sa.p[13] = llb2; sa.p[14] = aab1; sa.p[15] = aab2;
    sa.p[16] = lab1; sa.p[17] = lab2;
    sa.dst = swzbase; sa.lane_pts = (const u32*)lane_pts; sa.dflag = dflag;
    swz_kernel<<<SWZ1_BLOCKS, 256, 0, stream>>>(sa);

    // ---- K2 ----
    EncFillArgs ea;
    ea.x0 = lane_pts; ea.x1 = agent_hist;
    ea.w1a = lw1s; ea.b1a = lb1b; ea.w2a = lw2s; ea.b2a = lb2b; ea.w3a = lw3s; ea.b3a = lb3b;
    ea.w1b = aw1s; ea.b1b = ab1b; ea.w2b = aw2s; ea.b2b = ab2b; ea.w3b = aw3s; ea.b3b = ab3b;
    ea.out0 = lane_enc; ea.out1 = agent_enc;
    ea.dflag = dflag;
    ea.e_ll = e_ll; ea.e_aa = e_aa; ea.e_la = e_la;
    ea.deg = deg;
    ea.col_ll = col_ll; ea.col_aa = col_aa; ea.col_la = col_la;
    ea.gsrc[0] = llw1; ea.gsrc[1] = llw2; ea.gsrc[2] = aaw1;
    ea.gsrc[3] = aaw2; ea.gsrc[4] = law1; ea.gsrc[5] = law2;
    ea.swzdst = swzbase;
    enc_fill_kernel<<<EF_TOTAL, 256, 0, stream>>>(ea);

    // ---- K3 ----
    Gnn2Args ga;
    ga.node_ll = lane_enc;  ga.col_ll = col_ll; ga.deg_ll = deg;
    ga.w1_ll = llw1s; ga.b1_ll = llb1b; ga.w2_ll = llw2s; ga.b2_ll = llb2b;
    ga.out_ll = out_lane; ga.fin_ll = lane_fin;
    ga.node_aa = agent_enc; ga.col_aa = col_aa; ga.deg_aa = deg + N_LANEC;
    ga.w1_aa = aaw1s; ga.b1_aa = aab1b; ga.w2_aa = aaw2s; ga.b2_aa = aab2b; ga.out_aa = agent_mid;
    gnn2_kernel<<<(N_LANEC + N_AGENTC) / 16, 256, 0, stream>>>(ga);

    // ---- K4 ----
    gnn_la_kernel<<<N_AGENTC / 16, 256, 0, stream>>>(
        agent_mid, lane_fin, col_la, deg + N_LANEC + N_AGENTC,
        law1s, lab1b, law2s, lab2b, out_agent);
}

// Round 7
// 308.189 us; speedup vs baseline: 3.6109x; 3.6109x over previous
//
#include <hip/hip_runtime.h>

// ---- problem constants (from reference) ----
#define N_LANEC  20000
#define N_AGENTC 4000
#define PTS      20
#define FD       8
#define HD       128
#define E_LLC    640000
#define E_AAC    128000
#define E_LAC    200000

// per-partition caps: deg/8 ~ Poisson(4 | 4 | 6.25); P(overflow) < 1e-9
#define CAP8_LL 24
#define CAP8_AA 24
#define CAP8_LA 28
#define NPART   8      // pseudo-XCD partitions (blockIdx & 7 under round-robin)

typedef unsigned short u16;
typedef unsigned int   u32;
typedef __attribute__((ext_vector_type(8))) short short8;   // 8 bf16 (4 VGPRs)
typedef __attribute__((ext_vector_type(4))) float f32x4;    // MFMA C/D

__device__ __forceinline__ float bf2f(u16 u) {
    union { u32 i; float f; } c; c.i = ((u32)u) << 16; return c.f;
}
__device__ __forceinline__ u16 f2bf(float f) {
    union { float f; u32 i; } c; c.f = f;
    u32 r = c.i + 0x7FFFu + ((c.i >> 16) & 1u);   // RNE
    return (u16)(r >> 16);
}
__device__ __forceinline__ float ldf(const void* p, size_t i, int isf) {
    return isf ? ((const float*)p)[i] : bf2f(((const u16*)p)[i]);
}

// per-block input dtype detection (fp32 on this dataset)
__device__ __forceinline__ int detect_isf(const u32* x) {
    __shared__ int scnt;
    if (threadIdx.x == 0) scnt = 0;
    __syncthreads();
    u32 w = x[threadIdx.x & 255];
    int e = (int)((w >> 7) & 0xFFu);
    int ok = (e == 0) || (e >= 100 && e <= 140);
    atomicAdd(&scnt, ok);
    __syncthreads();
    return (scnt >= 200) ? 0 : 1;   // 1 = fp32
}

#define NE_TOT (E_LLC + E_AAC + E_LAC)
#define NDEG   (N_LANEC + 2 * N_AGENTC)   // 28000 counters per partition

// ---------------------------------------------------------------------------
// K1: enc-weight swizzle + biases + dflag + deg8 zeroing.
// ---------------------------------------------------------------------------
#define SWZ1_TOTAL  75264          // 4*16384 + 2*4096 + 12*128
#define SWZ1_BLOCKS 294            // == SWZ1_TOTAL/256 exactly
struct SwzArgs {
    const void* p[18]; u16* dst; const u32* lane_pts; int* dflag; int* deg8;
};
__global__ __launch_bounds__(256) void swz_kernel(SwzArgs a)
{
    const int tid = threadIdx.x;
    const int idx = blockIdx.x * 256 + tid;
    // zero deg8: 8*28000 ints = 56000 int4, one per thread
    if (idx < (NPART * NDEG) / 4)
        ((int4*)a.deg8)[idx] = (int4){0, 0, 0, 0};
    const int isf = detect_isf(a.lane_pts);
    if (blockIdx.x == 0 && tid == 0) *a.dflag = isf;

    const int sizes[18] = {16384,16384,16384,16384,4096,4096,
                           128,128,128,128,128,128,128,128,128,128,128,128};
    const int dsts[18]  = {0,16384,32768,49152,212992,217088,
                           221184,221312,221440,221568,221696,221824,
                           221952,222080,222208,222336,222464,222592};
    int seg = 0, rem = idx;
    while (rem >= sizes[seg]) { rem -= sizes[seg]; seg++; }
    if (seg >= 6) { a.dst[dsts[seg] + rem] = f2bf(ldf(a.p[seg], rem, isf)); return; }
    const int klim   = (seg < 4) ? 128 : 8;
    const int kshift = (seg < 4) ? 2 : 0;
    int j    = rem & 7;
    int lane = (rem >> 3) & 63;
    int t2   = rem >> 9;
    int ks   = t2 & ((1 << kshift) - 1);
    int nt   = t2 >> kshift;
    int k = ks * 32 + ((lane >> 4) << 3) + j;
    int n = nt * 16 + (lane & 15);
    a.dst[dsts[seg] + rem] = (k < klim) ? f2bf(ldf(a.p[seg], (size_t)k * HD + n, isf)) : (u16)0;
}

// ---------------------------------------------------------------------------
// K2: r4's high-TLP fill + enc + gswz, Bresenham-interleaved. Fill change
// (r5->r6): deg/col partitioned by blockIdx&7 (pseudo-XCD). Evidence: r5
// showed WRITE_SIZE 64->9.9MB when col writes became range-local; r2's
// padding null is explained by cross-XCD line-ownership migration (every
// counter line hit from all 8 XCDs regardless of padding). Partitioning by
// dispatch class keeps each deg/col line owned by ONE XCD's L2: atomics run
// at L2 rate, col lines written back once. Wrong XCD mapping only costs
// perf, never correctness.
// ---------------------------------------------------------------------------
#define ENC_BLOCKS   ((N_LANEC + N_AGENTC) / 4)        // 6000
#define FILL_THREADS ((NE_TOT + 3) / 4)                 // 242000
#define FILL_BLOCKS4 ((FILL_THREADS + 255) / 256)       // 946
#define GSWZ_TOTAL   147456                             // 3*32768 + 3*16384
#define GSWZ_BLOCKS  576                                // == GSWZ_TOTAL/256
#define AUX_BLOCKS   (FILL_BLOCKS4 + GSWZ_BLOCKS)       // 1522
#define EF_TOTAL     (ENC_BLOCKS + AUX_BLOCKS)          // 7522

struct EncFillArgs {
    const void* x0; const void* x1;
    const u16 *w1a, *b1a, *w2a, *b2a, *w3a, *b3a;
    const u16 *w1b, *b1b, *w2b, *b2b, *w3b, *b3b;
    u16 *out0, *out1;
    const int* dflag;
    const int *e_ll, *e_aa, *e_la;
    int *deg8;                     // [NPART][NDEG]
    u16 *col_ll, *col_aa, *col_la; // [NPART][nodes][CAP8_*]
    const void* gsrc[6];
    u16* swzdst;
};

__device__ __forceinline__ void fill4(const EncFillArgs& a, int fb)
{
    const int t  = fb * 256 + threadIdx.x;
    const int e4 = t * 4;
    if (e4 >= NE_TOT) return;
    const int part = (int)(blockIdx.x & (NPART - 1));
    const int* eb; int loc, cap, eoff, goff, nb; u16* col;
    if (e4 < E_LLC) {
        eb = a.e_ll; loc = e4;                  cap = CAP8_LL; col = a.col_ll;
        goff = 0;                nb = N_LANEC;  eoff = E_LLC;
    } else if (e4 < E_LLC + E_AAC) {
        eb = a.e_aa; loc = e4 - E_LLC;          cap = CAP8_AA; col = a.col_aa;
        goff = N_LANEC;          nb = N_AGENTC; eoff = E_AAC;
    } else {
        eb = a.e_la; loc = e4 - E_LLC - E_AAC;  cap = CAP8_LA; col = a.col_la;
        goff = N_LANEC + N_AGENTC; nb = N_AGENTC; eoff = E_LAC;
    }
    const int4 s4 = *(const int4*)&eb[loc];
    const int4 d4 = *(const int4*)&eb[eoff + loc];
    int* deg = a.deg8 + (size_t)part * NDEG + goff;
    // 4 independent atomics in flight; partition-local lines stay in one L2
    const int p0 = atomicAdd(&deg[d4.x], 1);
    const int p1 = atomicAdd(&deg[d4.y], 1);
    const int p2 = atomicAdd(&deg[d4.z], 1);
    const int p3 = atomicAdd(&deg[d4.w], 1);
    u16* cb = col + (size_t)part * nb * cap;
    if (p0 < cap) cb[(size_t)d4.x * cap + p0] = (u16)s4.x;
    if (p1 < cap) cb[(size_t)d4.y * cap + p1] = (u16)s4.y;
    if (p2 < cap) cb[(size_t)d4.z * cap + p2] = (u16)s4.z;
    if (p3 < cap) cb[(size_t)d4.w * cap + p3] = (u16)s4.w;
}

__device__ __forceinline__ void gswz(const EncFillArgs& a, int gb)
{
    const int isf = *a.dflag;
    int idx = gb * 256 + threadIdx.x;
    const int sizes[6] = {32768,16384,32768,16384,32768,16384};
    const int dsts[6]  = {65536,98304,114688,147456,163840,196608};
    int seg = 0, rem = idx;
    while (rem >= sizes[seg]) { rem -= sizes[seg]; seg++; }
    const int kshift = (seg & 1) ? 2 : 3;
    const int klim   = (seg & 1) ? 128 : 256;
    int j    = rem & 7;
    int lane = (rem >> 3) & 63;
    int t2   = rem >> 9;
    int ks   = t2 & ((1 << kshift) - 1);
    int nt   = t2 >> kshift;
    int k = ks * 32 + ((lane >> 4) << 3) + j;
    int n = nt * 16 + (lane & 15);
    a.swzdst[dsts[seg] + rem] =
        (k < klim) ? f2bf(ldf(a.gsrc[seg], (size_t)k * HD + n, isf)) : (u16)0;
}

__device__ void enc_body(const EncFillArgs& fa, int bid)
{
    const int tid = threadIdx.x;
    const int NT = 4;
    __shared__ __align__(16) u16 a_lds[NT * PTS][HD + 8];
    __shared__ int msI[NT][HD];

    const int isf = *fa.dflag;
    const int isLane = (bid < N_LANEC / 4);
    const void* x  = isLane ? fa.x0 : fa.x1;
    const u16* w1s = isLane ? fa.w1a : fa.w1b;
    const u16* b1  = isLane ? fa.b1a : fa.b1b;
    const u16* w2s = isLane ? fa.w2a : fa.w2b;
    const u16* b2  = isLane ? fa.b2a : fa.b2b;
    const u16* w3s = isLane ? fa.w3a : fa.w3b;
    const u16* b3  = isLane ? fa.b3a : fa.b3b;
    u16* out = isLane ? fa.out0 : fa.out1;
    const int n0 = (isLane ? bid : bid - N_LANEC / 4) * NT;

    const int lane = tid & 63;
    const int wv   = tid >> 6;
    const int l15  = lane & 15;
    const int quad = lane >> 4;

    for (int idx = tid; idx < NT * HD; idx += 256) ((int*)msI)[idx] = 0;

    short8 afr[5];
    #pragma unroll
    for (int mt = 0; mt < 5; mt++) afr[mt] = (short8){0,0,0,0,0,0,0,0};
    if (quad == 0) {
        #pragma unroll
        for (int mt = 0; mt < 5; mt++) {
            const int m  = mt * 16 + l15;
            const int nn = m / 20;
            const size_t xb = ((size_t)n0 * 20 + m) * 8;
            const size_t rb = (((size_t)(n0 + nn)) * 20 + 19) * 8;
            float f[8];
            if (isf) {
                const float* xf = (const float*)x;
                const float4 lo = *(const float4*)(xf + xb);
                const float4 hi = *(const float4*)(xf + xb + 4);
                f[0] = lo.x - xf[rb]; f[1] = lo.y - xf[rb + 1];
                f[2] = lo.z; f[3] = lo.w;
                f[4] = hi.x; f[5] = hi.y; f[6] = hi.z; f[7] = hi.w;
            } else {
                const u16* xu = (const u16*)x;
                #pragma unroll
                for (int k = 0; k < 8; k++) f[k] = bf2f(xu[xb + k]);
                f[0] -= bf2f(xu[rb]); f[1] -= bf2f(xu[rb + 1]);
            }
            short8 av;
            #pragma unroll
            for (int k = 0; k < 8; k++) av[k] = (short)f2bf(f[k]);
            afr[mt] = av;
        }
    }
    #pragma unroll
    for (int nt2 = 0; nt2 < 2; nt2++) {
        const int ntg = wv * 2 + nt2;
        const float b1v = bf2f(b1[ntg * 16 + l15]);
        const short8 bf = *(const short8*)&w1s[(((size_t)ntg) * 64 + lane) * 8];
        #pragma unroll
        for (int mt = 0; mt < 5; mt++) {
            f32x4 c = { b1v, b1v, b1v, b1v };
            c = __builtin_amdgcn_mfma_f32_16x16x32_bf16(afr[mt], bf, c, 0, 0, 0);
            #pragma unroll
            for (int r = 0; r < 4; r++)
                a_lds[mt * 16 + quad * 4 + r][ntg * 16 + l15] = f2bf(fmaxf(c[r], 0.f));
        }
    }
    __syncthreads();                                   // barrier 1

    short8 bfr[2][4];
    float b2v[2];
    #pragma unroll
    for (int nt2 = 0; nt2 < 2; nt2++) {
        const int ntg = wv * 2 + nt2;
        b2v[nt2] = bf2f(b2[ntg * 16 + l15]);
        #pragma unroll
        for (int ks = 0; ks < 4; ks++)
            bfr[nt2][ks] = *(const short8*)&w2s[(((size_t)(ntg * 4 + ks)) * 64 + lane) * 8];
    }
    const int col0 = (wv * 2 + 0) * 16 + l15;
    const int col1 = (wv * 2 + 1) * 16 + l15;
    float rm0 = 0.f, rm1 = 0.f;
    int curnode = 0;
    for (int mt = 0; mt < 5; mt++) {
        short8 af[4];
        #pragma unroll
        for (int ks = 0; ks < 4; ks++)
            af[ks] = *(const short8*)&a_lds[mt * 16 + l15][ks * 32 + quad * 8];
        f32x4 c0 = { b2v[0], b2v[0], b2v[0], b2v[0] };
        f32x4 c1 = { b2v[1], b2v[1], b2v[1], b2v[1] };
        #pragma unroll
        for (int ks = 0; ks < 4; ks++) {
            c0 = __builtin_amdgcn_mfma_f32_16x16x32_bf16(af[ks], bfr[0][ks], c0, 0, 0, 0);
            c1 = __builtin_amdgcn_mfma_f32_16x16x32_bf16(af[ks], bfr[1][ks], c1, 0, 0, 0);
        }
        #pragma unroll
        for (int r = 0; r < 4; r++) {
            const int m = mt * 16 + quad * 4 + r;
            const int nd = m / PTS;
            if (nd != curnode) {
                atomicMax(&msI[curnode][col0], __float_as_int(rm0));
                atomicMax(&msI[curnode][col1], __float_as_int(rm1));
                rm0 = 0.f; rm1 = 0.f; curnode = nd;
            }
            rm0 = fmaxf(rm0, c0[r]);
            rm1 = fmaxf(rm1, c1[r]);
        }
    }
    atomicMax(&msI[curnode][col0], __float_as_int(rm0));
    atomicMax(&msI[curnode][col1], __float_as_int(rm1));
    __syncthreads();                                   // barrier 2

    short8 a3[4];
    #pragma unroll
    for (int ks = 0; ks < 4; ks++) {
        short8 av = (short8){0,0,0,0,0,0,0,0};
        if (l15 < NT) {
            const int* row = &msI[l15][ks * 32 + quad * 8];
            #pragma unroll
            for (int k = 0; k < 8; k++) av[k] = (short)f2bf(__int_as_float(row[k]));
        }
        a3[ks] = av;
    }
    #pragma unroll
    for (int nt2 = 0; nt2 < 2; nt2++) {
        const int ntg = wv * 2 + nt2;
        const float b3v = bf2f(b3[ntg * 16 + l15]);
        f32x4 c = { b3v, b3v, b3v, b3v };
        #pragma unroll
        for (int ks = 0; ks < 4; ks++) {
            short8 b = *(const short8*)&w3s[(((size_t)(ntg * 4 + ks)) * 64 + lane) * 8];
            c = __builtin_amdgcn_mfma_f32_16x16x32_bf16(a3[ks], b, c, 0, 0, 0);
        }
        #pragma unroll
        for (int r = 0; r < 4; r++) {
            const int row = quad * 4 + r;
            if (row < NT)
                out[(size_t)(n0 + row) * HD + ntg * 16 + l15] = f2bf(fmaxf(c[r], 0.f));
        }
    }
}

__global__ __launch_bounds__(256) void enc_fill_kernel(EncFillArgs a)
{
    const int i  = (int)blockIdx.x;
    const int a0 = (int)(((long long)i * AUX_BLOCKS) / EF_TOTAL);
    const int a1 = (int)(((long long)(i + 1) * AUX_BLOCKS) / EF_TOTAL);
    if (a1 > a0) {
        const int f0 = (int)(((long long)a0 * FILL_BLOCKS4) / AUX_BLOCKS);
        const int f1 = (int)(((long long)(a0 + 1) * FILL_BLOCKS4) / AUX_BLOCKS);
        if (f1 > f0) fill4(a, f0);
        else         gswz(a, a0 - f1);
        return;
    }
    enc_body(a, i - a0);
}

// ---------------------------------------------------------------------------
// K3/K4: fused gather + edge-GNN MLP (r4-verified vectorized gather), now
// over 8 per-partition sub-buckets. degp points at deg8+goff; partition x's
// counter for node d is degp[x*NDEG+d]. OUT_MODE: 0=f32, 1=bf16, 2=f32+bf16.
// ---------------------------------------------------------------------------
template<int OUT_MODE>
__device__ __forceinline__ void gnn_body(
    int n0, const u16* __restrict__ node, const u16* __restrict__ src,
    const u16* __restrict__ col, const int* __restrict__ degp, int cap, int nnodes,
    const u16* __restrict__ w1s, const u16* __restrict__ b1,
    const u16* __restrict__ w2s, const u16* __restrict__ b2,
    void* __restrict__ outv, u16* __restrict__ out2)
{
    __shared__ __align__(16) u16 cats[16][2 * HD + 8];
    __shared__ __align__(16) u16 hb[16][HD + 8];
    const int tid  = threadIdx.x;
    const int lane = tid & 63;
    const int wv   = tid >> 6;
    const int l15  = lane & 15;
    const int quad = lane >> 4;

    const u32* node32 = (const u32*)node;
    for (int idx = tid; idx < 16 * 64; idx += 256) {
        int nn = idx >> 6, k2 = idx & 63;
        *(u32*)&cats[nn][k2 * 2] = node32[(size_t)(n0 + nn) * 64 + k2];
    }
    const int slot = lane >> 4;      // neighbor sub-stream 0..3
    const int fg   = lane & 15;      // feature group: feats fg*8..fg*8+7
    for (int t = 0; t < 4; t++) {
        const int dn = wv * 4 + t;
        const int d  = n0 + dn;
        int dv = 0;
        float acc[8] = {0.f,0.f,0.f,0.f,0.f,0.f,0.f,0.f};
        for (int x = 0; x < NPART; x++) {
            const int c  = degp[x * NDEG + d];
            dv += c;
            const int cx = min(c, cap);
            const u16* cb = col + ((size_t)x * nnodes + d) * cap;
            for (int e = slot; e < cx; e += 4) {
                const int r = (int)cb[e];
                const short8 v = *(const short8*)&src[(size_t)r * HD + fg * 8];
                #pragma unroll
                for (int k = 0; k < 8; k++) acc[k] += bf2f((u16)v[k]);
            }
        }
        const float inv = 1.f / fmaxf((float)dv, 1.f);
        #pragma unroll
        for (int k = 0; k < 8; k++) {
            acc[k] += __shfl_xor(acc[k], 16);
            acc[k] += __shfl_xor(acc[k], 32);
        }
        if (slot == 0) {
            short8 o;
            #pragma unroll
            for (int k = 0; k < 8; k++) o[k] = (short)f2bf(acc[k] * inv);
            *(short8*)&cats[dn][HD + fg * 8] = o;
        }
    }
    __syncthreads();

    #pragma unroll
    for (int nt2 = 0; nt2 < 2; nt2++) {
        const int ntg = wv * 2 + nt2;
        const float b1v = bf2f(b1[ntg * 16 + l15]);
        f32x4 c = { b1v, b1v, b1v, b1v };
        #pragma unroll
        for (int ks = 0; ks < 8; ks++) {
            short8 a = *(const short8*)&cats[l15][ks * 32 + quad * 8];
            short8 b = *(const short8*)&w1s[(((size_t)(ntg * 8 + ks)) * 64 + lane) * 8];
            c = __builtin_amdgcn_mfma_f32_16x16x32_bf16(a, b, c, 0, 0, 0);
        }
        #pragma unroll
        for (int r = 0; r < 4; r++)
            hb[quad * 4 + r][ntg * 16 + l15] = f2bf(fmaxf(c[r], 0.f));
    }
    __syncthreads();

    #pragma unroll
    for (int nt2 = 0; nt2 < 2; nt2++) {
        const int ntg = wv * 2 + nt2;
        const float b2v = bf2f(b2[ntg * 16 + l15]);
        f32x4 c = { b2v, b2v, b2v, b2v };
        #pragma unroll
        for (int ks = 0; ks < 4; ks++) {
            short8 a = *(const short8*)&hb[l15][ks * 32 + quad * 8];
            short8 b = *(const short8*)&w2s[(((size_t)(ntg * 4 + ks)) * 64 + lane) * 8];
            c = __builtin_amdgcn_mfma_f32_16x16x32_bf16(a, b, c, 0, 0, 0);
        }
        #pragma unroll
        for (int r = 0; r < 4; r++) {
            const int row = quad * 4 + r;
            size_t o = (size_t)(n0 + row) * HD + ntg * 16 + l15;
            float res = bf2f(node[o]) + fmaxf(c[r], 0.f);
            if (OUT_MODE == 1) ((u16*)outv)[o] = f2bf(res);
            else {
                ((float*)outv)[o] = res;
                if (OUT_MODE == 2) out2[o] = f2bf(res);
            }
        }
    }
}

struct Gnn2Args {
    const u16* node_ll; const u16* col_ll; const int* deg8;
    const u16 *w1_ll, *b1_ll, *w2_ll, *b2_ll; float* out_ll; u16* fin_ll;
    const u16* node_aa; const u16* col_aa;
    const u16 *w1_aa, *b1_aa, *w2_aa, *b2_aa; u16* out_aa;
};
__global__ __launch_bounds__(256) void gnn2_kernel(Gnn2Args a) {
    if (blockIdx.x < N_LANEC / 16)
        gnn_body<2>(blockIdx.x * 16, a.node_ll, a.node_ll, a.col_ll,
                    a.deg8, CAP8_LL, N_LANEC,
                    a.w1_ll, a.b1_ll, a.w2_ll, a.b2_ll, a.out_ll, a.fin_ll);
    else
        gnn_body<1>((blockIdx.x - N_LANEC / 16) * 16, a.node_aa, a.node_aa,
                    a.col_aa, a.deg8 + N_LANEC, CAP8_AA, N_AGENTC,
                    a.w1_aa, a.b1_aa, a.w2_aa, a.b2_aa, a.out_aa, nullptr);
}
__global__ __launch_bounds__(256) void gnn_la_kernel(
    const u16* node, const u16* src, const u16* col, const int* deg8,
    const u16* w1s, const u16* b1, const u16* w2s, const u16* b2, float* out) {
    gnn_body<0>(blockIdx.x * 16, node, src, col,
                deg8 + N_LANEC + N_AGENTC, CAP8_LA, N_AGENTC,
                w1s, b1, w2s, b2, out, nullptr);
}

// ---------------------------------------------------------------------------
extern "C" void kernel_launch(void* const* d_in, const int* in_sizes, int n_in,
                              void* d_out, int out_size, void* d_ws, size_t ws_size,
                              hipStream_t stream)
{
    const void* lane_pts   = d_in[0];
    const void* agent_hist = d_in[1];
    const int* e_ll = (const int*)d_in[2];
    const int* e_aa = (const int*)d_in[3];
    const int* e_la = (const int*)d_in[4];
    const void *lw1 = d_in[5],  *lb1 = d_in[6],  *lw2 = d_in[7],  *lb2 = d_in[8],
               *lw3 = d_in[9],  *lb3 = d_in[10];
    const void *aw1 = d_in[11], *ab1 = d_in[12], *aw2 = d_in[13], *ab2 = d_in[14],
               *aw3 = d_in[15], *ab3 = d_in[16];
    const void *llw1 = d_in[17], *llb1 = d_in[18], *llw2 = d_in[19], *llb2 = d_in[20];
    const void *aaw1 = d_in[21], *aab1 = d_in[22], *aaw2 = d_in[23], *aab2 = d_in[24];
    const void *law1 = d_in[25], *lab1 = d_in[26], *law2 = d_in[27], *lab2 = d_in[28];

    // ---- workspace layout (~24.6 MB) ----
    #define SWZ_TOTAL 222720
    u16* sp = (u16*)d_ws;
    u16* swzbase = sp; sp += SWZ_TOTAL;
    u16* llw1s = swzbase + 65536;
    u16* llw2s = swzbase + 98304;
    u16* aaw1s = swzbase + 114688;
    u16* aaw2s = swzbase + 147456;
    u16* law1s = swzbase + 163840;
    u16* law2s = swzbase + 196608;
    u16* lw1s  = swzbase + 212992;
    u16* aw1s  = swzbase + 217088;
    u16* lw2s  = swzbase + 0;
    u16* aw2s  = swzbase + 16384;
    u16* lw3s  = swzbase + 32768;
    u16* aw3s  = swzbase + 49152;
    u16* lb1b  = swzbase + 221184;
    u16* lb2b  = swzbase + 221312;
    u16* lb3b  = swzbase + 221440;
    u16* ab1b  = swzbase + 221568;
    u16* ab2b  = swzbase + 221696;
    u16* ab3b  = swzbase + 221824;
    u16* llb1b = swzbase + 221952;
    u16* llb2b = swzbase + 222080;
    u16* aab1b = swzbase + 222208;
    u16* aab2b = swzbase + 222336;
    u16* lab1b = swzbase + 222464;
    u16* lab2b = swzbase + 222592;
    int* ip = (int*)sp;
    int* dflag = ip; ip += 4;
    int* deg8  = ip; ip += (size_t)NPART * NDEG;     // 224000 ints
    u16* hp = (u16*)ip;
    u16* col_ll = hp; hp += (size_t)NPART * N_LANEC * CAP8_LL;
    u16* col_aa = hp; hp += (size_t)NPART * N_AGENTC * CAP8_AA;
    u16* col_la = hp; hp += (size_t)NPART * N_AGENTC * CAP8_LA;
    u16* lane_enc  = hp; hp += (size_t)N_LANEC * HD;
    u16* agent_enc = hp; hp += (size_t)N_AGENTC * HD;
    u16* agent_mid = hp; hp += (size_t)N_AGENTC * HD;
    u16* lane_fin  = hp; hp += (size_t)N_LANEC * HD;

    float* out_lane  = (float*)d_out;
    float* out_agent = (float*)d_out + (size_t)N_LANEC * HD;

    // ---- K1 ----
    SwzArgs sa;
    sa.p[0] = lw2; sa.p[1] = aw2; sa.p[2] = lw3; sa.p[3] = aw3;
    sa.p[4] = lw1; sa.p[5] = aw1;
    sa.p[6] = lb1;  sa.p[7] = lb2;  sa.p[8] = lb3;
    sa.p[9] = ab1;  sa.p[10] = ab2; sa.p[11] = ab3;
    sa.p[12] = llb1; sa.p[13] = llb2; sa.p[14] = aab1; sa.p[15] = aab2;
    sa.p[16] = lab1; sa.p[17] = lab2;
    sa.dst = swzbase; sa.lane_pts = (const u32*)lane_pts; sa.dflag = dflag;
    sa.deg8 = deg8;
    swz_kernel<<<SWZ1_BLOCKS, 256, 0, stream>>>(sa);

    // ---- K2 ----
    EncFillArgs ea;
    ea.x0 = lane_pts; ea.x1 = agent_hist;
    ea.w1a = lw1s; ea.b1a = lb1b; ea.w2a = lw2s; ea.b2a = lb2b; ea.w3a = lw3s; ea.b3a = lb3b;
    ea.w1b = aw1s; ea.b1b = ab1b; ea.w2b = aw2s; ea.b2b = ab2b; ea.w3b = aw3s; ea.b3b = ab3b;
    ea.out0 = lane_enc; ea.out1 = agent_enc;
    ea.dflag = dflag;
    ea.e_ll = e_ll; ea.e_aa = e_aa; ea.e_la = e_la;
    ea.deg8 = deg8;
    ea.col_ll = col_ll; ea.col_aa = col_aa; ea.col_la = col_la;
    ea.gsrc[0] = llw1; ea.gsrc[1] = llw2; ea.gsrc[2] = aaw1;
    ea.gsrc[3] = aaw2; ea.gsrc[4] = law1; ea.gsrc[5] = law2;
    ea.swzdst = swzbase;
    enc_fill_kernel<<<EF_TOTAL, 256, 0, stream>>>(ea);

    // ---- K3 ----
    Gnn2Args ga;
    ga.node_ll = lane_enc;  ga.col_ll = col_ll; ga.deg8 = deg8;
    ga.w1_ll = llw1s; ga.b1_ll = llb1b; ga.w2_ll = llw2s; ga.b2_ll = llb2b;
    ga.out_ll = out_lane; ga.fin_ll = lane_fin;
    ga.node_aa = agent_enc; ga.col_aa = col_aa;
    ga.w1_aa = aaw1s; ga.b1_aa = aab1b; ga.w2_aa = aaw2s; ga.b2_aa = aab2b; ga.out_aa = agent_mid;
    gnn2_kernel<<<(N_LANEC + N_AGENTC) / 16, 256, 0, stream>>>(ga);

    // ---- K4 ----
    gnn_la_kernel<<<N_AGENTC / 16, 256, 0, stream>>>(
        agent_mid, lane_fin, col_la, deg8,
        law1s, lab1b, law2s, lab2b, out_agent);
}

// Round 8
// 250.810 us; speedup vs baseline: 4.4369x; 1.2288x over previous
//
#include <hip/hip_runtime.h>

// ---- problem constants (from reference) ----
#define N_LANEC  20000
#define N_AGENTC 4000
#define PTS      20
#define FD       8
#define HD       128
#define E_LLC    640000
#define E_AAC    128000
#define E_LAC    200000

#define CAP_LL 80     // deg ~ Binom(640k, 1/20k): mean 32; P(>80) < 1e-11
#define CAP_AA 80     // mean 32
#define CAP_LA 112    // mean 50; P(>112) < 1e-12

typedef unsigned short u16;
typedef unsigned int   u32;
typedef __attribute__((ext_vector_type(8))) short short8;   // 8 bf16 (4 VGPRs)
typedef __attribute__((ext_vector_type(4))) float f32x4;    // MFMA C/D

__device__ __forceinline__ float bf2f(u16 u) {
    union { u32 i; float f; } c; c.i = ((u32)u) << 16; return c.f;
}
__device__ __forceinline__ u16 f2bf(float f) {
    union { float f; u32 i; } c; c.f = f;
    u32 r = c.i + 0x7FFFu + ((c.i >> 16) & 1u);   // RNE
    return (u16)(r >> 16);
}
__device__ __forceinline__ float ldf(const void* p, size_t i, int isf) {
    return isf ? ((const float*)p)[i] : bf2f(((const u16*)p)[i]);
}

// per-block input dtype detection (fp32 on this dataset)
__device__ __forceinline__ int detect_isf(const u32* x) {
    __shared__ int scnt;
    if (threadIdx.x == 0) scnt = 0;
    __syncthreads();
    u32 w = x[threadIdx.x & 255];
    int e = (int)((w >> 7) & 0xFFu);
    int ok = (e == 0) || (e >= 100 && e <= 140);
    atomicAdd(&scnt, ok);
    __syncthreads();
    return (scnt >= 200) ? 0 : 1;   // 1 = fp32
}

#define NE_TOT (E_LLC + E_AAC + E_LAC)
#define NDEG   (N_LANEC + 2 * N_AGENTC)   // 28000 compact counters

// ---------------------------------------------------------------------------
// K1: enc-weight swizzle + biases + dflag + compact deg zeroing.
// (r2 proved counter-line padding neutral -> compact layout, 28000 ints.)
// ---------------------------------------------------------------------------
#define SWZ1_TOTAL  75264          // 4*16384 + 2*4096 + 12*128
#define SWZ1_BLOCKS 294            // == SWZ1_TOTAL/256 exactly
struct SwzArgs {
    const void* p[18]; u16* dst; const u32* lane_pts; int* dflag; int* deg;
};
__global__ __launch_bounds__(256) void swz_kernel(SwzArgs a)
{
    const int tid = threadIdx.x;
    const int idx = blockIdx.x * 256 + tid;
    if (idx < NDEG / 4) ((int4*)a.deg)[idx] = (int4){0, 0, 0, 0};
    const int isf = detect_isf(a.lane_pts);
    if (blockIdx.x == 0 && tid == 0) *a.dflag = isf;

    const int sizes[18] = {16384,16384,16384,16384,4096,4096,
                           128,128,128,128,128,128,128,128,128,128,128,128};
    const int dsts[18]  = {0,16384,32768,49152,212992,217088,
                           221184,221312,221440,221568,221696,221824,
                           221952,222080,222208,222336,222464,222592};
    int seg = 0, rem = idx;
    while (rem >= sizes[seg]) { rem -= sizes[seg]; seg++; }
    if (seg >= 6) { a.dst[dsts[seg] + rem] = f2bf(ldf(a.p[seg], rem, isf)); return; }
    const int klim   = (seg < 4) ? 128 : 8;
    const int kshift = (seg < 4) ? 2 : 0;
    int j    = rem & 7;
    int lane = (rem >> 3) & 63;
    int t2   = rem >> 9;
    int ks   = t2 & ((1 << kshift) - 1);
    int nt   = t2 >> kshift;
    int k = ks * 32 + ((lane >> 4) << 3) + j;
    int n = nt * 16 + (lane & 15);
    a.dst[dsts[seg] + rem] = (k < klim) ? f2bf(ldf(a.p[seg], (size_t)k * HD + n, isf)) : (u16)0;
}

// ---------------------------------------------------------------------------
// K2: PointNet encoders + single-bucket high-TLP edge fill + GNN-weight
// swizzle, Bresenham-interleaved (r4 structure = best verified, 280us).
// r7 lesson: partitioned buckets didn't speed the fill (fabric atomic
// issue-rate floor) and fragmented the gather. Bucket layout serves the
// READER.
// ---------------------------------------------------------------------------
#define ENC_BLOCKS   ((N_LANEC + N_AGENTC) / 4)        // 6000
#define FILL_THREADS ((NE_TOT + 3) / 4)                 // 242000
#define FILL_BLOCKS4 ((FILL_THREADS + 255) / 256)       // 946
#define GSWZ_TOTAL   147456                             // 3*32768 + 3*16384
#define GSWZ_BLOCKS  576                                // == GSWZ_TOTAL/256
#define AUX_BLOCKS   (FILL_BLOCKS4 + GSWZ_BLOCKS)       // 1522
#define EF_TOTAL     (ENC_BLOCKS + AUX_BLOCKS)          // 7522

struct EncFillArgs {
    const void* x0; const void* x1;
    const u16 *w1a, *b1a, *w2a, *b2a, *w3a, *b3a;
    const u16 *w1b, *b1b, *w2b, *b2b, *w3b, *b3b;
    u16 *out0, *out1;
    const int* dflag;
    const int *e_ll, *e_aa, *e_la;
    int *deg;                      // compact [NDEG]
    u16 *col_ll, *col_aa, *col_la;
    const void* gsrc[6];
    u16* swzdst;
};

__device__ __forceinline__ void fill4(const EncFillArgs& a, int fb)
{
    const int t  = fb * 256 + threadIdx.x;
    const int e4 = t * 4;
    if (e4 >= NE_TOT) return;
    const int* eb; int loc, cap, eoff; u16* col; int* deg;
    if (e4 < E_LLC) {
        eb = a.e_ll; loc = e4;                  cap = CAP_LL; col = a.col_ll;
        deg = a.deg;                            eoff = E_LLC;
    } else if (e4 < E_LLC + E_AAC) {
        eb = a.e_aa; loc = e4 - E_LLC;          cap = CAP_AA; col = a.col_aa;
        deg = a.deg + N_LANEC;                  eoff = E_AAC;
    } else {
        eb = a.e_la; loc = e4 - E_LLC - E_AAC;  cap = CAP_LA; col = a.col_la;
        deg = a.deg + N_LANEC + N_AGENTC;       eoff = E_LAC;
    }
    const int4 s4 = *(const int4*)&eb[loc];
    const int4 d4 = *(const int4*)&eb[eoff + loc];
    const int p0 = atomicAdd(&deg[d4.x], 1);
    const int p1 = atomicAdd(&deg[d4.y], 1);
    const int p2 = atomicAdd(&deg[d4.z], 1);
    const int p3 = atomicAdd(&deg[d4.w], 1);
    if (p0 < cap) __builtin_nontemporal_store((u16)s4.x, &col[(size_t)d4.x * cap + p0]);
    if (p1 < cap) __builtin_nontemporal_store((u16)s4.y, &col[(size_t)d4.y * cap + p1]);
    if (p2 < cap) __builtin_nontemporal_store((u16)s4.z, &col[(size_t)d4.z * cap + p2]);
    if (p3 < cap) __builtin_nontemporal_store((u16)s4.w, &col[(size_t)d4.w * cap + p3]);
}

__device__ __forceinline__ void gswz(const EncFillArgs& a, int gb)
{
    const int isf = *a.dflag;
    int idx = gb * 256 + threadIdx.x;
    const int sizes[6] = {32768,16384,32768,16384,32768,16384};
    const int dsts[6]  = {65536,98304,114688,147456,163840,196608};
    int seg = 0, rem = idx;
    while (rem >= sizes[seg]) { rem -= sizes[seg]; seg++; }
    const int kshift = (seg & 1) ? 2 : 3;
    const int klim   = (seg & 1) ? 128 : 256;
    int j    = rem & 7;
    int lane = (rem >> 3) & 63;
    int t2   = rem >> 9;
    int ks   = t2 & ((1 << kshift) - 1);
    int nt   = t2 >> kshift;
    int k = ks * 32 + ((lane >> 4) << 3) + j;
    int n = nt * 16 + (lane & 15);
    a.swzdst[dsts[seg] + rem] =
        (k < klim) ? f2bf(ldf(a.gsrc[seg], (size_t)k * HD + n, isf)) : (u16)0;
}

__device__ void enc_body(const EncFillArgs& fa, int bid)
{
    const int tid = threadIdx.x;
    const int NT = 4;
    __shared__ __align__(16) u16 a_lds[NT * PTS][HD + 8];
    __shared__ int msI[NT][HD];

    const int isf = *fa.dflag;
    const int isLane = (bid < N_LANEC / 4);
    const void* x  = isLane ? fa.x0 : fa.x1;
    const u16* w1s = isLane ? fa.w1a : fa.w1b;
    const u16* b1  = isLane ? fa.b1a : fa.b1b;
    const u16* w2s = isLane ? fa.w2a : fa.w2b;
    const u16* b2  = isLane ? fa.b2a : fa.b2b;
    const u16* w3s = isLane ? fa.w3a : fa.w3b;
    const u16* b3  = isLane ? fa.b3a : fa.b3b;
    u16* out = isLane ? fa.out0 : fa.out1;
    const int n0 = (isLane ? bid : bid - N_LANEC / 4) * NT;

    const int lane = tid & 63;
    const int wv   = tid >> 6;
    const int l15  = lane & 15;
    const int quad = lane >> 4;

    for (int idx = tid; idx < NT * HD; idx += 256) ((int*)msI)[idx] = 0;

    short8 afr[5];
    #pragma unroll
    for (int mt = 0; mt < 5; mt++) afr[mt] = (short8){0,0,0,0,0,0,0,0};
    if (quad == 0) {
        #pragma unroll
        for (int mt = 0; mt < 5; mt++) {
            const int m  = mt * 16 + l15;
            const int nn = m / 20;
            const size_t xb = ((size_t)n0 * 20 + m) * 8;
            const size_t rb = (((size_t)(n0 + nn)) * 20 + 19) * 8;
            float f[8];
            if (isf) {
                const float* xf = (const float*)x;
                const float4 lo = *(const float4*)(xf + xb);
                const float4 hi = *(const float4*)(xf + xb + 4);
                f[0] = lo.x - xf[rb]; f[1] = lo.y - xf[rb + 1];
                f[2] = lo.z; f[3] = lo.w;
                f[4] = hi.x; f[5] = hi.y; f[6] = hi.z; f[7] = hi.w;
            } else {
                const u16* xu = (const u16*)x;
                #pragma unroll
                for (int k = 0; k < 8; k++) f[k] = bf2f(xu[xb + k]);
                f[0] -= bf2f(xu[rb]); f[1] -= bf2f(xu[rb + 1]);
            }
            short8 av;
            #pragma unroll
            for (int k = 0; k < 8; k++) av[k] = (short)f2bf(f[k]);
            afr[mt] = av;
        }
    }
    #pragma unroll
    for (int nt2 = 0; nt2 < 2; nt2++) {
        const int ntg = wv * 2 + nt2;
        const float b1v = bf2f(b1[ntg * 16 + l15]);
        const short8 bf = *(const short8*)&w1s[(((size_t)ntg) * 64 + lane) * 8];
        #pragma unroll
        for (int mt = 0; mt < 5; mt++) {
            f32x4 c = { b1v, b1v, b1v, b1v };
            c = __builtin_amdgcn_mfma_f32_16x16x32_bf16(afr[mt], bf, c, 0, 0, 0);
            #pragma unroll
            for (int r = 0; r < 4; r++)
                a_lds[mt * 16 + quad * 4 + r][ntg * 16 + l15] = f2bf(fmaxf(c[r], 0.f));
        }
    }
    __syncthreads();                                   // barrier 1

    short8 bfr[2][4];
    float b2v[2];
    #pragma unroll
    for (int nt2 = 0; nt2 < 2; nt2++) {
        const int ntg = wv * 2 + nt2;
        b2v[nt2] = bf2f(b2[ntg * 16 + l15]);
        #pragma unroll
        for (int ks = 0; ks < 4; ks++)
            bfr[nt2][ks] = *(const short8*)&w2s[(((size_t)(ntg * 4 + ks)) * 64 + lane) * 8];
    }
    const int col0 = (wv * 2 + 0) * 16 + l15;
    const int col1 = (wv * 2 + 1) * 16 + l15;
    float rm0 = 0.f, rm1 = 0.f;
    int curnode = 0;
    for (int mt = 0; mt < 5; mt++) {
        short8 af[4];
        #pragma unroll
        for (int ks = 0; ks < 4; ks++)
            af[ks] = *(const short8*)&a_lds[mt * 16 + l15][ks * 32 + quad * 8];
        f32x4 c0 = { b2v[0], b2v[0], b2v[0], b2v[0] };
        f32x4 c1 = { b2v[1], b2v[1], b2v[1], b2v[1] };
        #pragma unroll
        for (int ks = 0; ks < 4; ks++) {
            c0 = __builtin_amdgcn_mfma_f32_16x16x32_bf16(af[ks], bfr[0][ks], c0, 0, 0, 0);
            c1 = __builtin_amdgcn_mfma_f32_16x16x32_bf16(af[ks], bfr[1][ks], c1, 0, 0, 0);
        }
        #pragma unroll
        for (int r = 0; r < 4; r++) {
            const int m = mt * 16 + quad * 4 + r;
            const int nd = m / PTS;
            if (nd != curnode) {
                atomicMax(&msI[curnode][col0], __float_as_int(rm0));
                atomicMax(&msI[curnode][col1], __float_as_int(rm1));
                rm0 = 0.f; rm1 = 0.f; curnode = nd;
            }
            rm0 = fmaxf(rm0, c0[r]);
            rm1 = fmaxf(rm1, c1[r]);
        }
    }
    atomicMax(&msI[curnode][col0], __float_as_int(rm0));
    atomicMax(&msI[curnode][col1], __float_as_int(rm1));
    __syncthreads();                                   // barrier 2

    short8 a3[4];
    #pragma unroll
    for (int ks = 0; ks < 4; ks++) {
        short8 av = (short8){0,0,0,0,0,0,0,0};
        if (l15 < NT) {
            const int* row = &msI[l15][ks * 32 + quad * 8];
            #pragma unroll
            for (int k = 0; k < 8; k++) av[k] = (short)f2bf(__int_as_float(row[k]));
        }
        a3[ks] = av;
    }
    #pragma unroll
    for (int nt2 = 0; nt2 < 2; nt2++) {
        const int ntg = wv * 2 + nt2;
        const float b3v = bf2f(b3[ntg * 16 + l15]);
        f32x4 c = { b3v, b3v, b3v, b3v };
        #pragma unroll
        for (int ks = 0; ks < 4; ks++) {
            short8 b = *(const short8*)&w3s[(((size_t)(ntg * 4 + ks)) * 64 + lane) * 8];
            c = __builtin_amdgcn_mfma_f32_16x16x32_bf16(a3[ks], b, c, 0, 0, 0);
        }
        #pragma unroll
        for (int r = 0; r < 4; r++) {
            const int row = quad * 4 + r;
            if (row < NT)
                out[(size_t)(n0 + row) * HD + ntg * 16 + l15] = f2bf(fmaxf(c[r], 0.f));
        }
    }
}

__global__ __launch_bounds__(256) void enc_fill_kernel(EncFillArgs a)
{
    const int i  = (int)blockIdx.x;
    const int a0 = (int)(((long long)i * AUX_BLOCKS) / EF_TOTAL);
    const int a1 = (int)(((long long)(i + 1) * AUX_BLOCKS) / EF_TOTAL);
    if (a1 > a0) {
        const int f0 = (int)(((long long)a0 * FILL_BLOCKS4) / AUX_BLOCKS);
        const int f1 = (int)(((long long)(a0 + 1) * FILL_BLOCKS4) / AUX_BLOCKS);
        if (f1 > f0) fill4(a, f0);
        else         gswz(a, a0 - f1);
        return;
    }
    enc_body(a, i - a0);
}

// ---------------------------------------------------------------------------
// K3/K4: fused gather + edge-GNN MLP. Gather = wave-per-node dwordx4 rows
// (r4) + 4-way MLP unroll (r8): fetch 4 bucket indices, issue 4 independent
// row loads back-to-back -> dependent chain depth /4.
// OUT_MODE: 0 = f32, 1 = bf16, 2 = f32 + bf16 copy.
// ---------------------------------------------------------------------------
template<int OUT_MODE>
__device__ __forceinline__ void gnn_body(
    int n0, const u16* __restrict__ node, const u16* __restrict__ src,
    const u16* __restrict__ col, const int* __restrict__ deg, int cap,
    const u16* __restrict__ w1s, const u16* __restrict__ b1,
    const u16* __restrict__ w2s, const u16* __restrict__ b2,
    void* __restrict__ outv, u16* __restrict__ out2)
{
    __shared__ __align__(16) u16 cats[16][2 * HD + 8];
    __shared__ __align__(16) u16 hb[16][HD + 8];
    const int tid  = threadIdx.x;
    const int lane = tid & 63;
    const int wv   = tid >> 6;
    const int l15  = lane & 15;
    const int quad = lane >> 4;

    const u32* node32 = (const u32*)node;
    for (int idx = tid; idx < 16 * 64; idx += 256) {
        int nn = idx >> 6, k2 = idx & 63;
        *(u32*)&cats[nn][k2 * 2] = node32[(size_t)(n0 + nn) * 64 + k2];
    }
    const int slot = lane >> 4;      // neighbor sub-stream 0..3
    const int fg   = lane & 15;      // feature group: feats fg*8..fg*8+7
    for (int t = 0; t < 4; t++) {
        const int dn = wv * 4 + t;
        const int d  = n0 + dn;
        const int dv = deg[d];
        const int cnt = min(dv, cap);
        const u16* cb = col + (size_t)d * cap;
        float acc[8] = {0.f,0.f,0.f,0.f,0.f,0.f,0.f,0.f};
        int e = slot;
        // 4-way: 4 independent row loads in flight per slot
        for (; e + 12 < cnt; e += 16) {
            const int r0 = (int)cb[e];
            const int r1 = (int)cb[e + 4];
            const int r2 = (int)cb[e + 8];
            const int r3 = (int)cb[e + 12];
            const short8 v0 = *(const short8*)&src[(size_t)r0 * HD + fg * 8];
            const short8 v1 = *(const short8*)&src[(size_t)r1 * HD + fg * 8];
            const short8 v2 = *(const short8*)&src[(size_t)r2 * HD + fg * 8];
            const short8 v3 = *(const short8*)&src[(size_t)r3 * HD + fg * 8];
            #pragma unroll
            for (int k = 0; k < 8; k++)
                acc[k] += (bf2f((u16)v0[k]) + bf2f((u16)v1[k]))
                        + (bf2f((u16)v2[k]) + bf2f((u16)v3[k]));
        }
        for (; e < cnt; e += 4) {
            const int r = (int)cb[e];
            const short8 v = *(const short8*)&src[(size_t)r * HD + fg * 8];
            #pragma unroll
            for (int k = 0; k < 8; k++) acc[k] += bf2f((u16)v[k]);
        }
        const float inv = 1.f / fmaxf((float)dv, 1.f);
        #pragma unroll
        for (int k = 0; k < 8; k++) {
            acc[k] += __shfl_xor(acc[k], 16);
            acc[k] += __shfl_xor(acc[k], 32);
        }
        if (slot == 0) {
            short8 o;
            #pragma unroll
            for (int k = 0; k < 8; k++) o[k] = (short)f2bf(acc[k] * inv);
            *(short8*)&cats[dn][HD + fg * 8] = o;
        }
    }
    __syncthreads();

    #pragma unroll
    for (int nt2 = 0; nt2 < 2; nt2++) {
        const int ntg = wv * 2 + nt2;
        const float b1v = bf2f(b1[ntg * 16 + l15]);
        f32x4 c = { b1v, b1v, b1v, b1v };
        #pragma unroll
        for (int ks = 0; ks < 8; ks++) {
            short8 a = *(const short8*)&cats[l15][ks * 32 + quad * 8];
            short8 b = *(const short8*)&w1s[(((size_t)(ntg * 8 + ks)) * 64 + lane) * 8];
            c = __builtin_amdgcn_mfma_f32_16x16x32_bf16(a, b, c, 0, 0, 0);
        }
        #pragma unroll
        for (int r = 0; r < 4; r++)
            hb[quad * 4 + r][ntg * 16 + l15] = f2bf(fmaxf(c[r], 0.f));
    }
    __syncthreads();

    #pragma unroll
    for (int nt2 = 0; nt2 < 2; nt2++) {
        const int ntg = wv * 2 + nt2;
        const float b2v = bf2f(b2[ntg * 16 + l15]);
        f32x4 c = { b2v, b2v, b2v, b2v };
        #pragma unroll
        for (int ks = 0; ks < 4; ks++) {
            short8 a = *(const short8*)&hb[l15][ks * 32 + quad * 8];
            short8 b = *(const short8*)&w2s[(((size_t)(ntg * 4 + ks)) * 64 + lane) * 8];
            c = __builtin_amdgcn_mfma_f32_16x16x32_bf16(a, b, c, 0, 0, 0);
        }
        #pragma unroll
        for (int r = 0; r < 4; r++) {
            const int row = quad * 4 + r;
            size_t o = (size_t)(n0 + row) * HD + ntg * 16 + l15;
            float res = bf2f(node[o]) + fmaxf(c[r], 0.f);
            if (OUT_MODE == 1) ((u16*)outv)[o] = f2bf(res);
            else {
                ((float*)outv)[o] = res;
                if (OUT_MODE == 2) out2[o] = f2bf(res);
            }
        }
    }
}

struct Gnn2Args {
    const u16* node_ll; const u16* col_ll; const int* deg_ll;
    const u16 *w1_ll, *b1_ll, *w2_ll, *b2_ll; float* out_ll; u16* fin_ll;
    const u16* node_aa; const u16* col_aa; const int* deg_aa;
    const u16 *w1_aa, *b1_aa, *w2_aa, *b2_aa; u16* out_aa;
};
__global__ __launch_bounds__(256) void gnn2_kernel(Gnn2Args a) {
    if (blockIdx.x < N_LANEC / 16)
        gnn_body<2>(blockIdx.x * 16, a.node_ll, a.node_ll, a.col_ll, a.deg_ll, CAP_LL,
                    a.w1_ll, a.b1_ll, a.w2_ll, a.b2_ll, a.out_ll, a.fin_ll);
    else
        gnn_body<1>((blockIdx.x - N_LANEC / 16) * 16, a.node_aa, a.node_aa,
                    a.col_aa, a.deg_aa, CAP_AA,
                    a.w1_aa, a.b1_aa, a.w2_aa, a.b2_aa, a.out_aa, nullptr);
}
__global__ __launch_bounds__(256) void gnn_la_kernel(
    const u16* node, const u16* src, const u16* col, const int* deg,
    const u16* w1s, const u16* b1, const u16* w2s, const u16* b2, float* out) {
    gnn_body<0>(blockIdx.x * 16, node, src, col, deg, CAP_LA,
                w1s, b1, w2s, b2, out, nullptr);
}

// ---------------------------------------------------------------------------
extern "C" void kernel_launch(void* const* d_in, const int* in_sizes, int n_in,
                              void* d_out, int out_size, void* d_ws, size_t ws_size,
                              hipStream_t stream)
{
    const void* lane_pts   = d_in[0];
    const void* agent_hist = d_in[1];
    const int* e_ll = (const int*)d_in[2];
    const int* e_aa = (const int*)d_in[3];
    const int* e_la = (const int*)d_in[4];
    const void *lw1 = d_in[5],  *lb1 = d_in[6],  *lw2 = d_in[7],  *lb2 = d_in[8],
               *lw3 = d_in[9],  *lb3 = d_in[10];
    const void *aw1 = d_in[11], *ab1 = d_in[12], *aw2 = d_in[13], *ab2 = d_in[14],
               *aw3 = d_in[15], *ab3 = d_in[16];
    const void *llw1 = d_in[17], *llb1 = d_in[18], *llw2 = d_in[19], *llb2 = d_in[20];
    const void *aaw1 = d_in[21], *aab1 = d_in[22], *aaw2 = d_in[23], *aab2 = d_in[24];
    const void *law1 = d_in[25], *lab1 = d_in[26], *law2 = d_in[27], *lab2 = d_in[28];

    // ---- workspace layout ----
    #define SWZ_TOTAL 222720
    u16* sp = (u16*)d_ws;
    u16* swzbase = sp; sp += SWZ_TOTAL;
    u16* llw1s = swzbase + 65536;
    u16* llw2s = swzbase + 98304;
    u16* aaw1s = swzbase + 114688;
    u16* aaw2s = swzbase + 147456;
    u16* law1s = swzbase + 163840;
    u16* law2s = swzbase + 196608;
    u16* lw1s  = swzbase + 212992;
    u16* aw1s  = swzbase + 217088;
    u16* lw2s  = swzbase + 0;
    u16* aw2s  = swzbase + 16384;
    u16* lw3s  = swzbase + 32768;
    u16* aw3s  = swzbase + 49152;
    u16* lb1b  = swzbase + 221184;
    u16* lb2b  = swzbase + 221312;
    u16* lb3b  = swzbase + 221440;
    u16* ab1b  = swzbase + 221568;
    u16* ab2b  = swzbase + 221696;
    u16* ab3b  = swzbase + 221824;
    u16* llb1b = swzbase + 221952;
    u16* llb2b = swzbase + 222080;
    u16* aab1b = swzbase + 222208;
    u16* aab2b = swzbase + 222336;
    u16* lab1b = swzbase + 222464;
    u16* lab2b = swzbase + 222592;
    int* ip = (int*)sp;
    int* dflag = ip; ip += 4;
    int* deg   = ip; ip += NDEG;            // compact 28000 ints
    u16* hp = (u16*)ip;
    u16* col_ll = hp; hp += (size_t)N_LANEC * CAP_LL;
    u16* col_aa = hp; hp += (size_t)N_AGENTC * CAP_AA;
    u16* col_la = hp; hp += (size_t)N_AGENTC * CAP_LA;
    u16* lane_enc  = hp; hp += (size_t)N_LANEC * HD;
    u16* agent_enc = hp; hp += (size_t)N_AGENTC * HD;
    u16* agent_mid = hp; hp += (size_t)N_AGENTC * HD;
    u16* lane_fin  = hp; hp += (size_t)N_LANEC * HD;

    float* out_lane  = (float*)d_out;
    float* out_agent = (float*)d_out + (size_t)N_LANEC * HD;

    // ---- K1 ----
    SwzArgs sa;
    sa.p[0] = lw2; sa.p[1] = aw2; sa.p[2] = lw3; sa.p[3] = aw3;
    sa.p[4] = lw1; sa.p[5] = aw1;
    sa.p[6] = lb1;  sa.p[7] = lb2;  sa.p[8] = lb3;
    sa.p[9] = ab1;  sa.p[10] = ab2; sa.p[11] = ab3;
    sa.p[12] = llb1; sa.p[13] = llb2; sa.p[14] = aab1; sa.p[15] = aab2;
    sa.p[16] = lab1; sa.p[17] = lab2;
    sa.dst = swzbase; sa.lane_pts = (const u32*)lane_pts; sa.dflag = dflag;
    sa.deg = deg;
    swz_kernel<<<SWZ1_BLOCKS, 256, 0, stream>>>(sa);

    // ---- K2 ----
    EncFillArgs ea;
    ea.x0 = lane_pts; ea.x1 = agent_hist;
    ea.w1a = lw1s; ea.b1a = lb1b; ea.w2a = lw2s; ea.b2a = lb2b; ea.w3a = lw3s; ea.b3a = lb3b;
    ea.w1b = aw1s; ea.b1b = ab1b; ea.w2b = aw2s; ea.b2b = ab2b; ea.w3b = aw3s; ea.b3b = ab3b;
    ea.out0 = lane_enc; ea.out1 = agent_enc;
    ea.dflag = dflag;
    ea.e_ll = e_ll; ea.e_aa = e_aa; ea.e_la = e_la;
    ea.deg = deg;
    ea.col_ll = col_ll; ea.col_aa = col_aa; ea.col_la = col_la;
    ea.gsrc[0] = llw1; ea.gsrc[1] = llw2; ea.gsrc[2] = aaw1;
    ea.gsrc[3] = aaw2; ea.gsrc[4] = law1; ea.gsrc[5] = law2;
    ea.swzdst = swzbase;
    enc_fill_kernel<<<EF_TOTAL, 256, 0, stream>>>(ea);

    // ---- K3 ----
    Gnn2Args ga;
    ga.node_ll = lane_enc;  ga.col_ll = col_ll; ga.deg_ll = deg;
    ga.w1_ll = llw1s; ga.b1_ll = llb1b; ga.w2_ll = llw2s; ga.b2_ll = llb2b;
    ga.out_ll = out_lane; ga.fin_ll = lane_fin;
    ga.node_aa = agent_enc; ga.col_aa = col_aa; ga.deg_aa = deg + N_LANEC;
    ga.w1_aa = aaw1s; ga.b1_aa = aab1b; ga.w2_aa = aaw2s; ga.b2_aa = aab2b; ga.out_aa = agent_mid;
    gnn2_kernel<<<(N_LANEC + N_AGENTC) / 16, 256, 0, stream>>>(ga);

    // ---- K4 ----
    gnn_la_kernel<<<N_AGENTC / 16, 256, 0, stream>>>(
        agent_mid, lane_fin, col_la, deg + N_LANEC + N_AGENTC,
        law1s, lab1b, law2s, lab2b, out_agent);
}